// Round 1
// baseline (1112.003 us; speedup 1.0000x reference)
//
#include <hip/hip_runtime.h>
#include <math.h>

#define NN 4000
#define EE 40000
#define NE 44000   // EE + NN self-loops
#define BB 2
#define TT 8
#define BT 16      // B*T graph instances
#define HH 4
#define CC 64
#define HC 256     // H*C
#define HLN 128    // lstm hidden
#define G4 512     // 4*HLN
#define FHN 128
#define KIN 32

__device__ __forceinline__ float sigf(float x){ return 1.0f/(1.0f+expf(-x)); }

// ---------------- CSR build (deterministic: atomic scatter + per-segment sort) ----------------
__global__ void k_zero(int* __restrict__ a, int n){
  int i = blockIdx.x*256+threadIdx.x;
  if (i < n) a[i] = 0;
}

__global__ void k_count(const int* __restrict__ dst, int* __restrict__ cnt){
  int e = blockIdx.x*256+threadIdx.x;
  if (e >= NE) return;
  int d = (e < EE) ? dst[e] : (e - EE);
  atomicAdd(&cnt[d], 1);
}

__global__ __launch_bounds__(1024) void k_scan(const int* __restrict__ cnt, int* __restrict__ ptr){
  __shared__ int part[1024];
  const int n = NN;
  int t = threadIdx.x;
  int base = t*4;
  int loc[4]; int s = 0;
  #pragma unroll
  for (int i=0;i<4;i++){ int c = (base+i < n) ? cnt[base+i] : 0; loc[i] = s; s += c; }
  part[t] = s;
  __syncthreads();
  for (int off=1; off<1024; off<<=1){
    int add = (t >= off) ? part[t-off] : 0;
    __syncthreads();
    part[t] += add;
    __syncthreads();
  }
  int ebase = (t > 0) ? part[t-1] : 0;
  #pragma unroll
  for (int i=0;i<4;i++){ if (base+i < n) ptr[base+i] = ebase + loc[i]; }
  if (t == 1023) ptr[n] = part[1023];
}

__global__ void k_scatter(const int* __restrict__ dst, const int* __restrict__ ptr,
                          int* __restrict__ cur, int* __restrict__ idxa){
  int e = blockIdx.x*256+threadIdx.x;
  if (e >= NE) return;
  int d = (e < EE) ? dst[e] : (e - EE);
  int pos = atomicAdd(&cur[d], 1);
  idxa[ptr[d]+pos] = e;
}

__global__ void k_sortseg(const int* __restrict__ ptr, int* __restrict__ idxa){
  int node = blockIdx.x*256+threadIdx.x;
  if (node >= NN) return;
  int p0 = ptr[node], p1 = ptr[node+1];
  for (int i=p0+1;i<p1;i++){
    int key = idxa[i]; int j = i-1;
    while (j >= p0 && idxa[j] > key){ idxa[j+1] = idxa[j]; j--; }
    idxa[j+1] = key;
  }
}

// ---------------- weight transpose for LSTM ----------------
__global__ void k_transpose(const float* __restrict__ Wih, const float* __restrict__ Whh,
                            float* __restrict__ WihT, float* __restrict__ WhhT){
  int i = blockIdx.x*256+threadIdx.x;
  if (i < 512*64){ WihT[(i & 63)*512 + (i >> 6)] = Wih[i]; }
  else if (i < 512*64 + 512*128){ int j = i - 512*64; WhhT[(j & 127)*512 + (j >> 7)] = Whh[j]; }
}

// ---------------- GAT: h = x @ W   (M=BT*NN, N=256, K=32 or 64) ----------------
template<int K>
__global__ __launch_bounds__(256) void k_feat(const float* __restrict__ x, const float* __restrict__ W,
                                              float* __restrict__ h){
  __shared__ float xs[16*K];
  const int tid = threadIdx.x;
  const size_t row0 = (size_t)blockIdx.x * 16;
  const float* xp = x + row0*K;
  for (int i = tid; i < 16*K; i += 256) xs[i] = xp[i];
  __syncthreads();
  float acc[16];
  #pragma unroll
  for (int r=0;r<16;r++) acc[r] = 0.f;
  for (int k=0;k<K;k+=4){
    float4 xv[16];
    #pragma unroll
    for (int r=0;r<16;r++) xv[r] = *(const float4*)&xs[r*K+k];
    #pragma unroll
    for (int kk=0;kk<4;kk++){
      float w = W[(k+kk)*HC + tid];
      #pragma unroll
      for (int r=0;r<16;r++) acc[r] = fmaf(((const float*)&xv[r])[kk], w, acc[r]);
    }
  }
  float* hp = h + row0*HC + tid;
  #pragma unroll
  for (int r=0;r<16;r++) hp[(size_t)r*HC] = acc[r];
}

// ---------------- attention coefficients per (inst,node,head) ----------------
__global__ void k_coef(const float* __restrict__ h, const float* __restrict__ a_src,
                       const float* __restrict__ a_dst, float* __restrict__ als, float* __restrict__ ald){
  int i = blockIdx.x*256+threadIdx.x;          // (inst*NN + n)*HH + head
  if (i >= BT*NN*HH) return;
  int head = i & 3; int node_inst = i >> 2;
  const float* hp = h + (size_t)node_inst*HC + head*CC;
  const float* as = a_src + head*CC;
  const float* ad = a_dst + head*CC;
  float s1 = 0.f, s2 = 0.f;
  for (int c=0;c<CC;c++){ float v = hp[c]; s1 = fmaf(v, as[c], s1); s2 = fmaf(v, ad[c], s2); }
  als[i] = s1; ald[i] = s2;
}

// ---------------- edge logits (leaky_relu 0.2) ----------------
__global__ void k_logits(const int* __restrict__ e0, const int* __restrict__ e1,
                         const float* __restrict__ als, const float* __restrict__ ald,
                         float* __restrict__ logit){
  int i = blockIdx.x*256+threadIdx.x;          // inst*NE + e
  if (i >= BT*NE) return;
  int inst = i / NE; int e = i % NE;
  int s = (e < EE) ? e0[e] : (e - EE);
  int d = (e < EE) ? e1[e] : (e - EE);
  const float* ap = als + ((size_t)inst*NN + s)*HH;
  const float* bp = ald + ((size_t)inst*NN + d)*HH;
  float4 out;
  float* o = (float*)&out;
  #pragma unroll
  for (int hh=0; hh<4; hh++){ float v = ap[hh]+bp[hh]; o[hh] = (v >= 0.f) ? v : 0.2f*v; }
  *(float4*)&logit[(size_t)i*4] = out;
}

// ---------------- segment softmax over incoming edges (overwrite logits with alpha) ----------------
__global__ void k_alpha(const int* __restrict__ ptr, const int* __restrict__ idxa,
                        float* __restrict__ logit){
  int i = blockIdx.x*256+threadIdx.x;          // (inst*NN + n)*HH + head
  if (i >= BT*NN*HH) return;
  int hh = i & 3; int node = (i >> 2) % NN; int inst = (i >> 2) / NN;
  int p0 = ptr[node], p1 = ptr[node+1];
  const size_t base = (size_t)inst*NE;
  float m = -1e30f;
  for (int p=p0;p<p1;p++){ float v = logit[(base + idxa[p])*4 + hh]; m = fmaxf(m, v); }
  float den = 0.f;
  for (int p=p0;p<p1;p++){ den += expf(logit[(base + idxa[p])*4 + hh] - m); }
  float inv = 1.f/den;
  for (int p=p0;p<p1;p++){ size_t q = (base + idxa[p])*4 + hh; logit[q] = expf(logit[q]-m)*inv; }
}

// ---------------- aggregate: out[n,c] = relu( mean_h sum_e alpha*h[src] + bias ) ----------------
__global__ __launch_bounds__(256) void k_aggr(const int* __restrict__ ptr, const int* __restrict__ idxa,
                       const int* __restrict__ e0, const float* __restrict__ alpha,
                       const float* __restrict__ h, const float* __restrict__ bias,
                       float* __restrict__ out){
  int i = blockIdx.x*256+threadIdx.x;          // (inst*NN + n)*CC + c
  if (i >= BT*NN*CC) return;
  int c = i & 63; int node = (i >> 6) % NN; int inst = (i >> 6) / NN;
  int p0 = ptr[node], p1 = ptr[node+1];
  float s = 0.f;
  for (int p=p0;p<p1;p++){
    int e = idxa[p];
    int src = (e < EE) ? e0[e] : (e - EE);
    const float4 a = *(const float4*)&alpha[((size_t)inst*NE + e)*4];
    const float* hp = h + ((size_t)inst*NN + src)*HC + c;
    s = fmaf(a.x, hp[0], s);
    s = fmaf(a.y, hp[64], s);
    s = fmaf(a.z, hp[128], s);
    s = fmaf(a.w, hp[192], s);
  }
  out[i] = fmaxf(0.25f*s + bias[c], 0.f);
}

// ---------------- persistent LSTM: 8 rows/block, all 8 steps, h/c in LDS ----------------
__global__ __launch_bounds__(256) void k_lstm(const float* __restrict__ g,
    const float* __restrict__ WihT, const float* __restrict__ WhhT,
    const float* __restrict__ b_ih, const float* __restrict__ b_hh,
    float* __restrict__ hT){
  __shared__ float xs[8*CC];    // 2 KB
  __shared__ float hs[8*HLN];   // 4 KB
  __shared__ float cs[8*HLN];   // 4 KB
  __shared__ float zs[8*G4];    // 16 KB
  const int tid = threadIdx.x;
  const int r0 = blockIdx.x*8;          // rows r0..r0+7, row = b*NN+n   (NN%8==0 -> same b)
  const int b = r0 / NN;
  const int n0 = r0 % NN;
  const int j0 = tid;                   // owns cols j0, j0+256
  const float bias0 = b_ih[j0] + b_hh[j0];
  const float bias1 = b_ih[j0+256] + b_hh[j0+256];
  for (int i=tid;i<8*HLN;i+=256){ hs[i]=0.f; cs[i]=0.f; }
  const int gu  = tid & 127;
  const int gr0 = (tid >> 7)*4;
  __syncthreads();
  for (int t=0;t<TT;t++){
    const float* gx = g + (((size_t)(b*TT+t))*NN + n0)*CC;
    for (int i=tid;i<8*CC;i+=256) xs[i] = gx[i];
    __syncthreads();
    float accA[8], accB[8];
    #pragma unroll
    for (int r=0;r<8;r++){ accA[r]=bias0; accB[r]=bias1; }
    for (int k=0;k<CC;k+=4){                  // x part, K=64
      float4 xv[8];
      #pragma unroll
      for (int r=0;r<8;r++) xv[r] = *(const float4*)&xs[r*CC+k];
      #pragma unroll
      for (int kk=0;kk<4;kk++){
        float wa = WihT[(k+kk)*G4 + j0];
        float wb = WihT[(k+kk)*G4 + j0 + 256];
        #pragma unroll
        for (int r=0;r<8;r++){
          float xvv = ((const float*)&xv[r])[kk];
          accA[r] = fmaf(xvv, wa, accA[r]);
          accB[r] = fmaf(xvv, wb, accB[r]);
        }
      }
    }
    for (int k=0;k<HLN;k+=4){                 // h part, K=128
      float4 hv[8];
      #pragma unroll
      for (int r=0;r<8;r++) hv[r] = *(const float4*)&hs[r*HLN+k];
      #pragma unroll
      for (int kk=0;kk<4;kk++){
        float wa = WhhT[(k+kk)*G4 + j0];
        float wb = WhhT[(k+kk)*G4 + j0 + 256];
        #pragma unroll
        for (int r=0;r<8;r++){
          float hvv = ((const float*)&hv[r])[kk];
          accA[r] = fmaf(hvv, wa, accA[r]);
          accB[r] = fmaf(hvv, wb, accB[r]);
        }
      }
    }
    #pragma unroll
    for (int r=0;r<8;r++){ zs[r*G4 + j0] = accA[r]; zs[r*G4 + j0 + 256] = accB[r]; }
    __syncthreads();
    #pragma unroll
    for (int rr=0;rr<4;rr++){
      int r = gr0 + rr;
      float zi = zs[r*G4 + gu];
      float zf = zs[r*G4 + gu + HLN];
      float zg = zs[r*G4 + gu + 2*HLN];
      float zo = zs[r*G4 + gu + 3*HLN];
      float c = sigf(zf)*cs[r*HLN+gu] + sigf(zi)*tanhf(zg);
      cs[r*HLN+gu] = c;
      float hval = sigf(zo)*tanhf(c);
      hs[r*HLN+gu] = hval;
      if (t == TT-1) hT[((size_t)(r0+r))*HLN + gu] = hval;
    }
    __syncthreads();
  }
}

// ---------------- fusion MLP + output dot ----------------
__global__ __launch_bounds__(128) void k_fuse(const float* __restrict__ hT, const float* __restrict__ g,
      const float* __restrict__ Wf, const float* __restrict__ bfv,
      const float* __restrict__ Wo, const float* __restrict__ bo,
      float* __restrict__ out){
  __shared__ float cat[HLN+CC];
  __shared__ float red[FHN];
  const int row = blockIdx.x;            // b*NN + n
  const int tid = threadIdx.x;
  cat[tid] = hT[(size_t)row*HLN + tid];
  if (tid < CC){
    int b = row / NN, n = row % NN;
    cat[HLN+tid] = g[(((size_t)(b*TT + (TT-1)))*NN + n)*CC + tid];
  }
  __syncthreads();
  float acc = bfv[tid];
  for (int k=0;k<HLN+CC;k++) acc = fmaf(cat[k], Wf[k*FHN + tid], acc);
  acc = fmaxf(acc, 0.f);
  red[tid] = acc * Wo[tid];
  __syncthreads();
  for (int s=64; s>0; s>>=1){ if (tid < s) red[tid] += red[tid+s]; __syncthreads(); }
  if (tid == 0) out[row] = red[0] + bo[0];
}

// ---------------- launch ----------------
extern "C" void kernel_launch(void* const* d_in, const int* in_sizes, int n_in,
                              void* d_out, int out_size, void* d_ws, size_t ws_size,
                              hipStream_t stream) {
  const float* x_seq  = (const float*)d_in[0];
  const float* W1     = (const float*)d_in[1];
  const float* a_src1 = (const float*)d_in[2];
  const float* a_dst1 = (const float*)d_in[3];
  const float* b1     = (const float*)d_in[4];
  const float* W2     = (const float*)d_in[5];
  const float* a_src2 = (const float*)d_in[6];
  const float* a_dst2 = (const float*)d_in[7];
  const float* b2     = (const float*)d_in[8];
  const float* W_ih   = (const float*)d_in[9];
  const float* W_hh   = (const float*)d_in[10];
  const float* b_ih   = (const float*)d_in[11];
  const float* b_hh   = (const float*)d_in[12];
  const float* Wf     = (const float*)d_in[13];
  const float* bfv    = (const float*)d_in[14];
  const float* Wo     = (const float*)d_in[15];
  const float* bo     = (const float*)d_in[16];
  const int*   ei     = (const int*)d_in[17];
  const int* e_src = ei;
  const int* e_dst = ei + EE;
  float* out = (float*)d_out;

  char* w = (char*)d_ws;
  auto alloc = [&](size_t bytes)->char*{
    char* p = w; w += (bytes + 255) & ~(size_t)255; return p;
  };
  float* hbuf = (float*)alloc((size_t)BT*NN*HC*4);   // 65.5 MB, reused both layers
  float* als  = (float*)alloc((size_t)BT*NN*HH*4);
  float* ald  = (float*)alloc((size_t)BT*NN*HH*4);
  float* alp  = (float*)alloc((size_t)BT*NE*HH*4);   // logits -> alpha
  float* gat1 = (float*)alloc((size_t)BT*NN*CC*4);
  float* gbuf = (float*)alloc((size_t)BT*NN*CC*4);   // final GAT output g
  float* hT   = (float*)alloc((size_t)BB*NN*HLN*4);
  float* WihT = (float*)alloc((size_t)64*512*4);
  float* WhhT = (float*)alloc((size_t)128*512*4);
  int* cnt    = (int*)alloc((size_t)2*NN*4);
  int* cur    = cnt + NN;
  int* ptr    = (int*)alloc((size_t)(NN+1)*4);
  int* idxa   = (int*)alloc((size_t)NE*4);

  // CSR build (same graph for all 16 instances)
  k_zero<<<(2*NN+255)/256, 256, 0, stream>>>(cnt, 2*NN);
  k_count<<<(NE+255)/256, 256, 0, stream>>>(e_dst, cnt);
  k_scan<<<1, 1024, 0, stream>>>(cnt, ptr);
  k_scatter<<<(NE+255)/256, 256, 0, stream>>>(e_dst, ptr, cur, idxa);
  k_sortseg<<<(NN+255)/256, 256, 0, stream>>>(ptr, idxa);
  k_transpose<<<(512*192+255)/256, 256, 0, stream>>>(W_ih, W_hh, WihT, WhhT);

  // GAT layer 1
  k_feat<KIN><<<BT*NN/16, 256, 0, stream>>>(x_seq, W1, hbuf);
  k_coef<<<(BT*NN*HH+255)/256, 256, 0, stream>>>(hbuf, a_src1, a_dst1, als, ald);
  k_logits<<<(BT*NE+255)/256, 256, 0, stream>>>(e_src, e_dst, als, ald, alp);
  k_alpha<<<(BT*NN*HH+255)/256, 256, 0, stream>>>(ptr, idxa, alp);
  k_aggr<<<(BT*NN*CC+255)/256, 256, 0, stream>>>(ptr, idxa, e_src, alp, hbuf, b1, gat1);

  // GAT layer 2
  k_feat<CC><<<BT*NN/16, 256, 0, stream>>>(gat1, W2, hbuf);
  k_coef<<<(BT*NN*HH+255)/256, 256, 0, stream>>>(hbuf, a_src2, a_dst2, als, ald);
  k_logits<<<(BT*NE+255)/256, 256, 0, stream>>>(e_src, e_dst, als, ald, alp);
  k_alpha<<<(BT*NN*HH+255)/256, 256, 0, stream>>>(ptr, idxa, alp);
  k_aggr<<<(BT*NN*CC+255)/256, 256, 0, stream>>>(ptr, idxa, e_src, alp, hbuf, b2, gbuf);

  // LSTM over time (rows independent)
  k_lstm<<<BB*NN/8, 256, 0, stream>>>(gbuf, WihT, WhhT, b_ih, b_hh, hT);

  // Fusion + output
  k_fuse<<<BB*NN, 128, 0, stream>>>(hT, gbuf, Wf, bfv, Wo, bo, out);
}

// Round 2
// 807.282 us; speedup vs baseline: 1.3775x; 1.3775x over previous
//
#include <hip/hip_runtime.h>
#include <math.h>

#define NN 4000
#define EE 40000
#define NE 44000   // EE + NN self-loops
#define BB 2
#define TT 8
#define BT 16      // B*T graph instances
#define HH 4
#define CC 64
#define HC 256     // H*C
#define HLN 128    // lstm hidden
#define G4 512     // 4*HLN
#define FHN 128

__device__ __forceinline__ float sigf(float x){ return 1.0f/(1.0f+expf(-x)); }

// ---------------- CSR build (deterministic: atomic scatter + per-segment sort) ----------------
__global__ void k_zero(int* __restrict__ a, int n){
  int i = blockIdx.x*256+threadIdx.x;
  if (i < n) a[i] = 0;
}

__global__ void k_count(const int* __restrict__ dst, int* __restrict__ cnt){
  int e = blockIdx.x*256+threadIdx.x;
  if (e >= NE) return;
  int d = (e < EE) ? dst[e] : (e - EE);
  atomicAdd(&cnt[d], 1);
}

__global__ __launch_bounds__(1024) void k_scan(const int* __restrict__ cnt, int* __restrict__ ptr){
  __shared__ int part[1024];
  const int n = NN;
  int t = threadIdx.x;
  int base = t*4;
  int loc[4]; int s = 0;
  #pragma unroll
  for (int i=0;i<4;i++){ int c = (base+i < n) ? cnt[base+i] : 0; loc[i] = s; s += c; }
  part[t] = s;
  __syncthreads();
  for (int off=1; off<1024; off<<=1){
    int add = (t >= off) ? part[t-off] : 0;
    __syncthreads();
    part[t] += add;
    __syncthreads();
  }
  int ebase = (t > 0) ? part[t-1] : 0;
  #pragma unroll
  for (int i=0;i<4;i++){ if (base+i < n) ptr[base+i] = ebase + loc[i]; }
  if (t == 1023) ptr[n] = part[1023];
}

__global__ void k_scatter(const int* __restrict__ dst, const int* __restrict__ ptr,
                          int* __restrict__ cur, int* __restrict__ idxa){
  int e = blockIdx.x*256+threadIdx.x;
  if (e >= NE) return;
  int d = (e < EE) ? dst[e] : (e - EE);
  int pos = atomicAdd(&cur[d], 1);
  idxa[ptr[d]+pos] = e;
}

__global__ void k_sortseg(const int* __restrict__ ptr, int* __restrict__ idxa){
  int node = blockIdx.x*256+threadIdx.x;
  if (node >= NN) return;
  int p0 = ptr[node], p1 = ptr[node+1];
  for (int i=p0+1;i<p1;i++){
    int key = idxa[i]; int j = i-1;
    while (j >= p0 && idxa[j] > key){ idxa[j+1] = idxa[j]; j--; }
    idxa[j+1] = key;
  }
}

// ---------------- weight transpose for LSTM ----------------
__global__ void k_transpose(const float* __restrict__ Wih, const float* __restrict__ Whh,
                            float* __restrict__ WihT, float* __restrict__ WhhT){
  int i = blockIdx.x*256+threadIdx.x;
  if (i < 512*64){ WihT[(i & 63)*512 + (i >> 6)] = Wih[i]; }
  else if (i < 512*64 + 512*128){ int j = i - 512*64; WhhT[(j & 127)*512 + (j >> 7)] = Whh[j]; }
}

// ---------------- wtilde: per-head projected attention vectors  w~ = W_h @ a_h ----------------
// wt layout: ws1[4*32] | wd1[4*32] | ws2[4*64] | wd2[4*64]
__global__ void k_wtil(const float* __restrict__ W1, const float* __restrict__ as1, const float* __restrict__ ad1,
                       const float* __restrict__ W2, const float* __restrict__ as2, const float* __restrict__ ad2,
                       float* __restrict__ wt){
  int i = blockIdx.x*256 + threadIdx.x;
  if (i < 256){                      // layer1: sd*128 + h*32 + k
    int sd = i >> 7, h = (i >> 5) & 3, k = i & 31;
    const float* a = sd ? ad1 : as1;
    float s = 0.f;
    for (int c=0;c<CC;c++) s = fmaf(W1[k*HC + h*CC + c], a[h*CC + c], s);
    wt[sd*128 + h*32 + k] = s;
  } else if (i < 768){               // layer2: sd*256 + h*64 + k
    int j = i - 256;
    int sd = j >> 8, h = (j >> 6) & 3, k = j & 63;
    const float* a = sd ? ad2 : as2;
    float s = 0.f;
    for (int c=0;c<CC;c++) s = fmaf(W2[k*HC + h*CC + c], a[h*CC + c], s);
    wt[256 + sd*256 + h*64 + k] = s;
  }
}

// ---------------- attention coefficients: als[n,h] = x[n] . w~s_h ----------------
template<int K>
__global__ void k_coef2(const float* __restrict__ x, const float* __restrict__ wts,
                        const float* __restrict__ wtd,
                        float* __restrict__ als, float* __restrict__ ald){
  int i = blockIdx.x*256+threadIdx.x;          // (inst*NN + n)*HH + head
  if (i >= BT*NN*HH) return;
  int h = i & 3; int ni = i >> 2;
  const float* xp = x + (size_t)ni*K;
  const float* s = wts + h*K;
  const float* d = wtd + h*K;
  float s1 = 0.f, s2 = 0.f;
  for (int k=0;k<K;k+=4){
    float4 xv = *(const float4*)&xp[k];
    float4 sv = *(const float4*)&s[k];
    float4 dv = *(const float4*)&d[k];
    s1 = fmaf(xv.x,sv.x,fmaf(xv.y,sv.y,fmaf(xv.z,sv.z,fmaf(xv.w,sv.w,s1))));
    s2 = fmaf(xv.x,dv.x,fmaf(xv.y,dv.y,fmaf(xv.z,dv.z,fmaf(xv.w,dv.w,s2))));
  }
  als[i] = s1; ald[i] = s2;
}

// ---------------- edge logits (leaky_relu 0.2) ----------------
__global__ void k_logits(const int* __restrict__ e0, const int* __restrict__ e1,
                         const float* __restrict__ als, const float* __restrict__ ald,
                         float* __restrict__ logit){
  int i = blockIdx.x*256+threadIdx.x;          // inst*NE + e
  if (i >= BT*NE) return;
  int inst = i / NE; int e = i % NE;
  int s = (e < EE) ? e0[e] : (e - EE);
  int d = (e < EE) ? e1[e] : (e - EE);
  const float* ap = als + ((size_t)inst*NN + s)*HH;
  const float* bp = ald + ((size_t)inst*NN + d)*HH;
  float4 out;
  float* o = (float*)&out;
  #pragma unroll
  for (int hh=0; hh<4; hh++){ float v = ap[hh]+bp[hh]; o[hh] = (v >= 0.f) ? v : 0.2f*v; }
  *(float4*)&logit[(size_t)i*4] = out;
}

// ---------------- segment softmax over incoming edges (overwrite logits with alpha) ----------------
__global__ void k_alpha(const int* __restrict__ ptr, const int* __restrict__ idxa,
                        float* __restrict__ logit){
  int i = blockIdx.x*256+threadIdx.x;          // (inst*NN + n)*HH + head
  if (i >= BT*NN*HH) return;
  int hh = i & 3; int node = (i >> 2) % NN; int inst = (i >> 2) / NN;
  int p0 = ptr[node], p1 = ptr[node+1];
  const size_t base = (size_t)inst*NE;
  float m = -1e30f;
  for (int p=p0;p<p1;p++){ float v = logit[(base + idxa[p])*4 + hh]; m = fmaxf(m, v); }
  float den = 0.f;
  for (int p=p0;p<p1;p++){ den += expf(logit[(base + idxa[p])*4 + hh] - m); }
  float inv = 1.f/den;
  for (int p=p0;p<p1;p++){ size_t q = (base + idxa[p])*4 + hh; logit[q] = expf(logit[q]-m)*inv; }
}

// ---------------- fused GAT output: agg in x-space (LDS), then per-head GEMM + mean + relu ----------
// agg[n,h,k] = sum_e alpha[e,h] * x[src_e,k];  out[n,c] = relu(0.25*sum_{h,k} agg*W[k,h*64+c] + b[c])
template<int KF>
__global__ __launch_bounds__(256) void k_gat_out(const int* __restrict__ ptr, const int* __restrict__ idxa,
    const int* __restrict__ e0, const float* __restrict__ alpha, const float* __restrict__ xin,
    const float* __restrict__ W, const float* __restrict__ bias, float* __restrict__ out){
  __shared__ float aggs[16*HH*KF];
  const int tid = threadIdx.x;
  const int inst = blockIdx.y;
  const int node0 = blockIdx.x*16;
  const size_t abase = (size_t)inst*NE;
  const size_t xbase = (size_t)inst*NN;
  // Phase A: per-edge aggregation in input space (4 heads per item)
  for (int item = tid; item < 16*KF; item += 256){
    int nl = item / KF, k = item % KF;
    int node = node0 + nl;
    int p0 = ptr[node], p1 = ptr[node+1];
    float a0=0.f,a1=0.f,a2=0.f,a3=0.f;
    for (int p=p0;p<p1;p++){
      int e = idxa[p];
      int src = (e < EE) ? e0[e] : (e - EE);
      const float4 al = *(const float4*)&alpha[(abase+e)*4];
      float xv = xin[(xbase+src)*KF + k];
      a0 = fmaf(al.x, xv, a0); a1 = fmaf(al.y, xv, a1);
      a2 = fmaf(al.z, xv, a2); a3 = fmaf(al.w, xv, a3);
    }
    float* ap = &aggs[nl*(HH*KF) + k];
    ap[0*KF] = a0; ap[1*KF] = a1; ap[2*KF] = a2; ap[3*KF] = a3;
  }
  __syncthreads();
  // Phase B: out[n,c] = relu(0.25 * sum_h sum_k aggs[n][h*KF+k] * W[k*HC + h*64 + c] + b[c])
  const int c = tid & 63, rq = tid >> 6;       // 4 rows per thread
  float facc[4] = {0.f,0.f,0.f,0.f};
  for (int h=0;h<HH;h++){
    for (int k=0;k<KF;k+=4){
      float4 ag[4];
      #pragma unroll
      for (int r=0;r<4;r++) ag[r] = *(const float4*)&aggs[(rq*4+r)*(HH*KF) + h*KF + k];
      #pragma unroll
      for (int kk=0;kk<4;kk++){
        float w = W[(k+kk)*HC + h*CC + c];
        #pragma unroll
        for (int r=0;r<4;r++) facc[r] = fmaf(((const float*)&ag[r])[kk], w, facc[r]);
      }
    }
  }
  float bv = bias[c];
  #pragma unroll
  for (int r=0;r<4;r++){
    int node = node0 + rq*4 + r;
    out[(xbase + node)*CC + c] = fmaxf(0.25f*facc[r] + bv, 0.f);
  }
}

// ---------------- persistent LSTM: 16 rows/block, all 8 steps, h/c in LDS ----------------
__global__ __launch_bounds__(256) void k_lstm2(const float* __restrict__ g,
    const float* __restrict__ WihT, const float* __restrict__ WhhT,
    const float* __restrict__ b_ih, const float* __restrict__ b_hh,
    float* __restrict__ hT){
  __shared__ float xs[16*CC];    // 4 KB
  __shared__ float hs[16*HLN];   // 8 KB
  __shared__ float cs[16*HLN];   // 8 KB
  __shared__ float zs[16*G4];    // 32 KB
  const int tid = threadIdx.x;
  const int r0 = blockIdx.x*16;          // rows r0..r0+15, row = b*NN+n  (NN%16==0 -> same b)
  const int b = r0 / NN;
  const int n0 = r0 % NN;
  const int j2 = 2*tid;                  // cols j2, j2+1
  const float bias0 = b_ih[j2]   + b_hh[j2];
  const float bias1 = b_ih[j2+1] + b_hh[j2+1];
  for (int i=tid;i<16*HLN;i+=256){ hs[i]=0.f; cs[i]=0.f; }
  __syncthreads();
  for (int t=0;t<TT;t++){
    const float* gx = g + (((size_t)(b*TT+t))*NN + n0)*CC;
    ((float4*)xs)[tid] = ((const float4*)gx)[tid];      // 16*64 floats = 256 float4
    __syncthreads();
    float accA[16], accB[16];
    #pragma unroll
    for (int r=0;r<16;r++){ accA[r]=bias0; accB[r]=bias1; }
    // x part, K=64
    for (int k=0;k<CC;k+=4){
      float2 w[4];
      #pragma unroll
      for (int kk=0;kk<4;kk++) w[kk] = *(const float2*)&WihT[(k+kk)*G4 + j2];
      #pragma unroll
      for (int half=0; half<2; half++){
        float4 xv[8];
        #pragma unroll
        for (int r=0;r<8;r++) xv[r] = *(const float4*)&xs[(half*8+r)*CC + k];
        #pragma unroll
        for (int kk=0;kk<4;kk++){
          #pragma unroll
          for (int r=0;r<8;r++){
            float v = ((const float*)&xv[r])[kk];
            accA[half*8+r] = fmaf(v, w[kk].x, accA[half*8+r]);
            accB[half*8+r] = fmaf(v, w[kk].y, accB[half*8+r]);
          }
        }
      }
    }
    // h part, K=128
    for (int k=0;k<HLN;k+=4){
      float2 w[4];
      #pragma unroll
      for (int kk=0;kk<4;kk++) w[kk] = *(const float2*)&WhhT[(k+kk)*G4 + j2];
      #pragma unroll
      for (int half=0; half<2; half++){
        float4 hv[8];
        #pragma unroll
        for (int r=0;r<8;r++) hv[r] = *(const float4*)&hs[(half*8+r)*HLN + k];
        #pragma unroll
        for (int kk=0;kk<4;kk++){
          #pragma unroll
          for (int r=0;r<8;r++){
            float v = ((const float*)&hv[r])[kk];
            accA[half*8+r] = fmaf(v, w[kk].x, accA[half*8+r]);
            accB[half*8+r] = fmaf(v, w[kk].y, accB[half*8+r]);
          }
        }
      }
    }
    #pragma unroll
    for (int r=0;r<16;r++){
      float2 z2 = {accA[r], accB[r]};
      *(float2*)&zs[r*G4 + j2] = z2;
    }
    __syncthreads();
    // gates: 16 rows x 128 units
    #pragma unroll
    for (int q=0;q<8;q++){
      int id = tid + q*256; int r = id >> 7; int u = id & 127;
      float zi = zs[r*G4 + u];
      float zf = zs[r*G4 + u + HLN];
      float zg = zs[r*G4 + u + 2*HLN];
      float zo = zs[r*G4 + u + 3*HLN];
      float c = sigf(zf)*cs[r*HLN+u] + sigf(zi)*tanhf(zg);
      cs[r*HLN+u] = c;
      float hval = sigf(zo)*tanhf(c);
      hs[r*HLN+u] = hval;
      if (t == TT-1) hT[((size_t)(r0+r))*HLN + u] = hval;
    }
    __syncthreads();
  }
}

// ---------------- fusion MLP + output dot ----------------
__global__ __launch_bounds__(128) void k_fuse(const float* __restrict__ hT, const float* __restrict__ g,
      const float* __restrict__ Wf, const float* __restrict__ bfv,
      const float* __restrict__ Wo, const float* __restrict__ bo,
      float* __restrict__ out){
  __shared__ float cat[HLN+CC];
  __shared__ float red[FHN];
  const int row = blockIdx.x;            // b*NN + n
  const int tid = threadIdx.x;
  cat[tid] = hT[(size_t)row*HLN + tid];
  if (tid < CC){
    int b = row / NN, n = row % NN;
    cat[HLN+tid] = g[(((size_t)(b*TT + (TT-1)))*NN + n)*CC + tid];
  }
  __syncthreads();
  float acc = bfv[tid];
  for (int k=0;k<HLN+CC;k++) acc = fmaf(cat[k], Wf[k*FHN + tid], acc);
  acc = fmaxf(acc, 0.f);
  red[tid] = acc * Wo[tid];
  __syncthreads();
  for (int s=64; s>0; s>>=1){ if (tid < s) red[tid] += red[tid+s]; __syncthreads(); }
  if (tid == 0) out[row] = red[0] + bo[0];
}

// ---------------- launch ----------------
extern "C" void kernel_launch(void* const* d_in, const int* in_sizes, int n_in,
                              void* d_out, int out_size, void* d_ws, size_t ws_size,
                              hipStream_t stream) {
  const float* x_seq  = (const float*)d_in[0];
  const float* W1     = (const float*)d_in[1];
  const float* a_src1 = (const float*)d_in[2];
  const float* a_dst1 = (const float*)d_in[3];
  const float* b1     = (const float*)d_in[4];
  const float* W2     = (const float*)d_in[5];
  const float* a_src2 = (const float*)d_in[6];
  const float* a_dst2 = (const float*)d_in[7];
  const float* b2     = (const float*)d_in[8];
  const float* W_ih   = (const float*)d_in[9];
  const float* W_hh   = (const float*)d_in[10];
  const float* b_ih   = (const float*)d_in[11];
  const float* b_hh   = (const float*)d_in[12];
  const float* Wf     = (const float*)d_in[13];
  const float* bfv    = (const float*)d_in[14];
  const float* Wo     = (const float*)d_in[15];
  const float* bo     = (const float*)d_in[16];
  const int*   ei     = (const int*)d_in[17];
  const int* e_src = ei;
  const int* e_dst = ei + EE;
  float* out = (float*)d_out;

  char* w = (char*)d_ws;
  auto alloc = [&](size_t bytes)->char*{
    char* p = w; w += (bytes + 255) & ~(size_t)255; return p;
  };
  float* als  = (float*)alloc((size_t)BT*NN*HH*4);
  float* ald  = (float*)alloc((size_t)BT*NN*HH*4);
  float* alp  = (float*)alloc((size_t)BT*NE*HH*4);   // logits -> alpha
  float* gat1 = (float*)alloc((size_t)BT*NN*CC*4);
  float* gbuf = (float*)alloc((size_t)BT*NN*CC*4);   // final GAT output g
  float* hT   = (float*)alloc((size_t)BB*NN*HLN*4);
  float* WihT = (float*)alloc((size_t)64*512*4);
  float* WhhT = (float*)alloc((size_t)128*512*4);
  float* wt   = (float*)alloc((size_t)768*4);
  int* cnt    = (int*)alloc((size_t)2*NN*4);
  int* cur    = cnt + NN;
  int* ptr    = (int*)alloc((size_t)(NN+1)*4);
  int* idxa   = (int*)alloc((size_t)NE*4);

  // CSR build (same graph for all 16 instances)
  k_zero<<<(2*NN+255)/256, 256, 0, stream>>>(cnt, 2*NN);
  k_count<<<(NE+255)/256, 256, 0, stream>>>(e_dst, cnt);
  k_scan<<<1, 1024, 0, stream>>>(cnt, ptr);
  k_scatter<<<(NE+255)/256, 256, 0, stream>>>(e_dst, ptr, cur, idxa);
  k_sortseg<<<(NN+255)/256, 256, 0, stream>>>(ptr, idxa);
  k_transpose<<<(512*192+255)/256, 256, 0, stream>>>(W_ih, W_hh, WihT, WhhT);
  k_wtil<<<3, 256, 0, stream>>>(W1, a_src1, a_dst1, W2, a_src2, a_dst2, wt);

  // GAT layer 1 (aggregation in x-space: 32-dim gathers)
  k_coef2<32><<<(BT*NN*HH+255)/256, 256, 0, stream>>>(x_seq, wt, wt+128, als, ald);
  k_logits<<<(BT*NE+255)/256, 256, 0, stream>>>(e_src, e_dst, als, ald, alp);
  k_alpha<<<(BT*NN*HH+255)/256, 256, 0, stream>>>(ptr, idxa, alp);
  k_gat_out<32><<<dim3(NN/16, BT), 256, 0, stream>>>(ptr, idxa, e_src, alp, x_seq, W1, b1, gat1);

  // GAT layer 2 (64-dim gathers from L2-resident gat1)
  k_coef2<64><<<(BT*NN*HH+255)/256, 256, 0, stream>>>(gat1, wt+256, wt+512, als, ald);
  k_logits<<<(BT*NE+255)/256, 256, 0, stream>>>(e_src, e_dst, als, ald, alp);
  k_alpha<<<(BT*NN*HH+255)/256, 256, 0, stream>>>(ptr, idxa, alp);
  k_gat_out<64><<<dim3(NN/16, BT), 256, 0, stream>>>(ptr, idxa, e_src, alp, gat1, W2, b2, gbuf);

  // LSTM over time (rows independent; persistent, h/c in LDS)
  k_lstm2<<<BB*NN/16, 256, 0, stream>>>(gbuf, WihT, WhhT, b_ih, b_hh, hT);

  // Fusion + output
  k_fuse<<<BB*NN, 128, 0, stream>>>(hT, gbuf, Wf, bfv, Wo, bo, out);
}

// Round 3
// 608.257 us; speedup vs baseline: 1.8282x; 1.3272x over previous
//
#include <hip/hip_runtime.h>
#include <math.h>

#define NN 4000
#define EE 40000
#define NE 44000   // EE + NN self-loops
#define BB 2
#define TT 8
#define BT 16      // B*T graph instances
#define HH 4
#define CC 64
#define HC 256     // H*C
#define HLN 128    // lstm hidden
#define G4 512     // 4*HLN
#define FHN 128
#define ROWS 16    // lstm rows per block

__device__ __forceinline__ float sigf(float x){ return 1.0f/(1.0f+expf(-x)); }

// ---------------- CSR build (deterministic: atomic scatter + per-segment sort) ----------------
__global__ void k_zero(int* __restrict__ a, int n){
  int i = blockIdx.x*256+threadIdx.x;
  if (i < n) a[i] = 0;
}

__global__ void k_count(const int* __restrict__ dst, int* __restrict__ cnt){
  int e = blockIdx.x*256+threadIdx.x;
  if (e >= NE) return;
  int d = (e < EE) ? dst[e] : (e - EE);
  atomicAdd(&cnt[d], 1);
}

__global__ __launch_bounds__(1024) void k_scan(const int* __restrict__ cnt, int* __restrict__ ptr){
  __shared__ int part[1024];
  const int n = NN;
  int t = threadIdx.x;
  int base = t*4;
  int loc[4]; int s = 0;
  #pragma unroll
  for (int i=0;i<4;i++){ int c = (base+i < n) ? cnt[base+i] : 0; loc[i] = s; s += c; }
  part[t] = s;
  __syncthreads();
  for (int off=1; off<1024; off<<=1){
    int add = (t >= off) ? part[t-off] : 0;
    __syncthreads();
    part[t] += add;
    __syncthreads();
  }
  int ebase = (t > 0) ? part[t-1] : 0;
  #pragma unroll
  for (int i=0;i<4;i++){ if (base+i < n) ptr[base+i] = ebase + loc[i]; }
  if (t == 1023) ptr[n] = part[1023];
}

__global__ void k_scatter(const int* __restrict__ dst, const int* __restrict__ ptr,
                          int* __restrict__ cur, int* __restrict__ idxa){
  int e = blockIdx.x*256+threadIdx.x;
  if (e >= NE) return;
  int d = (e < EE) ? dst[e] : (e - EE);
  int pos = atomicAdd(&cur[d], 1);
  idxa[ptr[d]+pos] = e;
}

// sort each segment (deterministic order) and emit position-indexed src/dst
__global__ void k_sortseg(const int* __restrict__ ptr, int* __restrict__ idxa,
                          const int* __restrict__ e0, int* __restrict__ srcs, int* __restrict__ dstp){
  int node = blockIdx.x*256+threadIdx.x;
  if (node >= NN) return;
  int p0 = ptr[node], p1 = ptr[node+1];
  for (int i=p0+1;i<p1;i++){
    int key = idxa[i]; int j = i-1;
    while (j >= p0 && idxa[j] > key){ idxa[j+1] = idxa[j]; j--; }
    idxa[j+1] = key;
  }
  for (int p=p0;p<p1;p++){
    int e = idxa[p];
    srcs[p] = (e < EE) ? e0[e] : (e - EE);
    dstp[p] = node;
  }
}

// ---------------- LSTM weight prep: gate-interleaved transpose + fused bias ----------------
// WihT4[k*512 + u*4 + g] = W_ih[(g*128+u)*64 + k];  WhhT4 analog;  bias4[u*4+g] = b_ih+b_hh
__global__ void k_wtrans(const float* __restrict__ Wih, const float* __restrict__ Whh,
                         const float* __restrict__ bih, const float* __restrict__ bhh,
                         float* __restrict__ WihT4, float* __restrict__ WhhT4,
                         float* __restrict__ bias4){
  int i = blockIdx.x*256+threadIdx.x;
  if (i < 64*512){
    int k = i >> 9, cu = i & 511, u = cu >> 2, gg = cu & 3;
    WihT4[i] = Wih[(gg*128+u)*64 + k];
  } else if (i < 64*512 + 128*512){
    int j = i - 64*512;
    int k = j >> 9, cu = j & 511, u = cu >> 2, gg = cu & 3;
    WhhT4[j] = Whh[(gg*128+u)*128 + k];
  } else if (i < 64*512 + 128*512 + 512){
    int cu = i - (64*512 + 128*512);
    int u = cu >> 2, gg = cu & 3;
    bias4[cu] = bih[gg*128+u] + bhh[gg*128+u];
  }
}

// ---------------- wtilde: per-head projected attention vectors  w~ = W_h @ a_h ----------------
// wt layout: ws1[4*32] | wd1[4*32] | ws2[4*64] | wd2[4*64]
__global__ void k_wtil(const float* __restrict__ W1, const float* __restrict__ as1, const float* __restrict__ ad1,
                       const float* __restrict__ W2, const float* __restrict__ as2, const float* __restrict__ ad2,
                       float* __restrict__ wt){
  int i = blockIdx.x*256 + threadIdx.x;
  if (i < 256){                      // layer1: sd*128 + h*32 + k
    int sd = i >> 7, h = (i >> 5) & 3, k = i & 31;
    const float* a = sd ? ad1 : as1;
    float s = 0.f;
    for (int c=0;c<CC;c++) s = fmaf(W1[k*HC + h*CC + c], a[h*CC + c], s);
    wt[sd*128 + h*32 + k] = s;
  } else if (i < 768){               // layer2: sd*256 + h*64 + k
    int j = i - 256;
    int sd = j >> 8, h = (j >> 6) & 3, k = j & 63;
    const float* a = sd ? ad2 : as2;
    float s = 0.f;
    for (int c=0;c<CC;c++) s = fmaf(W2[k*HC + h*CC + c], a[h*CC + c], s);
    wt[256 + sd*256 + h*64 + k] = s;
  }
}

// ---------------- attention coefficients: als[n,h] = x[n] . w~s_h ----------------
template<int K>
__global__ void k_coef2(const float* __restrict__ x, const float* __restrict__ wts,
                        const float* __restrict__ wtd,
                        float* __restrict__ als, float* __restrict__ ald){
  int i = blockIdx.x*256+threadIdx.x;          // (inst*NN + n)*HH + head
  if (i >= BT*NN*HH) return;
  int h = i & 3; int ni = i >> 2;
  const float* xp = x + (size_t)ni*K;
  const float* s = wts + h*K;
  const float* d = wtd + h*K;
  float s1 = 0.f, s2 = 0.f;
  for (int k=0;k<K;k+=4){
    float4 xv = *(const float4*)&xp[k];
    float4 sv = *(const float4*)&s[k];
    float4 dv = *(const float4*)&d[k];
    s1 = fmaf(xv.x,sv.x,fmaf(xv.y,sv.y,fmaf(xv.z,sv.z,fmaf(xv.w,sv.w,s1))));
    s2 = fmaf(xv.x,dv.x,fmaf(xv.y,dv.y,fmaf(xv.z,dv.z,fmaf(xv.w,dv.w,s2))));
  }
  als[i] = s1; ald[i] = s2;
}

// ---------------- edge logits, CSR-position indexed (streaming writes) ----------------
__global__ void k_logits(const int* __restrict__ srcs, const int* __restrict__ dstp,
                         const float* __restrict__ als, const float* __restrict__ ald,
                         float* __restrict__ logit){
  int i = blockIdx.x*256+threadIdx.x;          // inst*NE + p
  if (i >= BT*NE) return;
  int inst = i / NE; int p = i % NE;
  int s = srcs[p];
  int d = dstp[p];
  const float4 av = *(const float4*)&als[((size_t)inst*NN + s)*HH];
  const float4 bv = *(const float4*)&ald[((size_t)inst*NN + d)*HH];
  float4 out;
  float* o = (float*)&out;
  const float* ap = (const float*)&av;
  const float* bp = (const float*)&bv;
  #pragma unroll
  for (int hh=0; hh<4; hh++){ float v = ap[hh]+bp[hh]; o[hh] = (v >= 0.f) ? v : 0.2f*v; }
  *(float4*)&logit[(size_t)i*4] = out;
}

// ---------------- segment softmax (streaming: positions are contiguous per dst) ----------------
__global__ void k_alpha(const int* __restrict__ ptr, float* __restrict__ logit){
  int i = blockIdx.x*256+threadIdx.x;          // (inst*NN + n)*HH + head
  if (i >= BT*NN*HH) return;
  int hh = i & 3; int node = (i >> 2) % NN; int inst = (i >> 2) / NN;
  int p0 = ptr[node], p1 = ptr[node+1];
  const size_t base = (size_t)inst*NE;
  float m = -1e30f;
  for (int p=p0;p<p1;p++){ float v = logit[(base + p)*4 + hh]; m = fmaxf(m, v); }
  float den = 0.f;
  for (int p=p0;p<p1;p++){ den += expf(logit[(base + p)*4 + hh] - m); }
  float inv = 1.f/den;
  for (int p=p0;p<p1;p++){ size_t q = (base + p)*4 + hh; logit[q] = expf(logit[q]-m)*inv; }
}

// ---------------- fused GAT output: agg in x-space (LDS), then per-head GEMM + mean + relu ----------
template<int KF>
__global__ __launch_bounds__(256) void k_gat_out(const int* __restrict__ ptr, const int* __restrict__ srcs,
    const float* __restrict__ alphap, const float* __restrict__ xin,
    const float* __restrict__ W, const float* __restrict__ bias, float* __restrict__ out){
  __shared__ float aggs[16*HH*KF];
  const int tid = threadIdx.x;
  const int inst = blockIdx.y;
  const int node0 = blockIdx.x*16;
  const size_t abase = (size_t)inst*NE;
  const size_t xbase = (size_t)inst*NN;
  // Phase A: per-edge aggregation in input space (4 heads per item); alpha/src streamed by position
  for (int item = tid; item < 16*KF; item += 256){
    int nl = item / KF, k = item % KF;
    int node = node0 + nl;
    int p0 = ptr[node], p1 = ptr[node+1];
    float a0=0.f,a1=0.f,a2=0.f,a3=0.f;
    for (int p=p0;p<p1;p++){
      const float4 al = *(const float4*)&alphap[(abase+p)*4];
      int src = srcs[p];
      float xv = xin[(xbase+src)*KF + k];
      a0 = fmaf(al.x, xv, a0); a1 = fmaf(al.y, xv, a1);
      a2 = fmaf(al.z, xv, a2); a3 = fmaf(al.w, xv, a3);
    }
    float* ap = &aggs[nl*(HH*KF) + k];
    ap[0*KF] = a0; ap[1*KF] = a1; ap[2*KF] = a2; ap[3*KF] = a3;
  }
  __syncthreads();
  // Phase B: out[n,c] = relu(0.25 * sum_h sum_k aggs[n][h*KF+k] * W[k*HC + h*64 + c] + b[c])
  const int c = tid & 63, rq = tid >> 6;       // 4 rows per thread
  float facc[4] = {0.f,0.f,0.f,0.f};
  for (int h=0;h<HH;h++){
    for (int k=0;k<KF;k+=4){
      float4 ag[4];
      #pragma unroll
      for (int r=0;r<4;r++) ag[r] = *(const float4*)&aggs[(rq*4+r)*(HH*KF) + h*KF + k];
      #pragma unroll
      for (int kk=0;kk<4;kk++){
        float w = W[(k+kk)*HC + h*CC + c];
        #pragma unroll
        for (int r=0;r<4;r++) facc[r] = fmaf(((const float*)&ag[r])[kk], w, facc[r]);
      }
    }
  }
  float bv = bias[c];
  #pragma unroll
  for (int r=0;r<4;r++){
    int node = node0 + rq*4 + r;
    out[(xbase + node)*CC + c] = fmaxf(0.25f*facc[r] + bv, 0.f);
  }
}

// ---------------- persistent LSTM (4-gate/unit threads) + fused output MLP ----------------
__global__ __launch_bounds__(512) void k_lstm3(const float* __restrict__ g,
    const float* __restrict__ WihT4, const float* __restrict__ WhhT4,
    const float* __restrict__ bias4, const float* __restrict__ Wf,
    const float* __restrict__ bfv, const float* __restrict__ Wo,
    const float* __restrict__ bo, float* __restrict__ out){
  __shared__ float hs[2][ROWS][HLN];   // 16 KB ping-pong hidden
  __shared__ float xs[2][ROWS][CC];    // 8 KB ping-pong input
  const int tid = threadIdx.x;
  const int u = tid & 127;             // unit
  const int r04 = (tid >> 7) * 4;      // 4 rows per thread
  const int r0 = blockIdx.x*ROWS;      // rows r0..r0+15, row = b*NN+n (NN%16==0 -> same b)
  const int b = r0 / NN;
  const int n0 = r0 % NN;
  const float4 bv = *(const float4*)&bias4[u*4];
  for (int i=tid;i<ROWS*HLN;i+=512) ((float*)hs[0])[i] = 0.f;
  {
    const float4* gx = (const float4*)(g + ((size_t)(b*TT)*NN + n0)*CC);
    if (tid < ROWS*CC/4) ((float4*)xs[0])[tid] = gx[tid];
  }
  float creg[4] = {0.f,0.f,0.f,0.f};
  __syncthreads();
  int cur = 0;
  for (int t=0;t<TT;t++){
    if (t+1 < TT){
      const float4* gx = (const float4*)(g + ((size_t)(b*TT+t+1)*NN + n0)*CC);
      if (tid < ROWS*CC/4) ((float4*)xs[cur^1])[tid] = gx[tid];
    }
    float acc[4][4];
    #pragma unroll
    for (int r=0;r<4;r++){
      acc[r][0]=bv.x; acc[r][1]=bv.y; acc[r][2]=bv.z; acc[r][3]=bv.w;
    }
    // x part, K=64
    for (int k=0;k<CC;k+=4){
      float4 w[4];
      #pragma unroll
      for (int kk=0;kk<4;kk++) w[kk] = *(const float4*)&WihT4[(k+kk)*G4 + u*4];
      #pragma unroll
      for (int r=0;r<4;r++){
        float4 xv = *(const float4*)&xs[cur][r04+r][k];
        #pragma unroll
        for (int kk=0;kk<4;kk++){
          float v = ((const float*)&xv)[kk];
          acc[r][0] = fmaf(v, ((const float*)&w[kk])[0], acc[r][0]);
          acc[r][1] = fmaf(v, ((const float*)&w[kk])[1], acc[r][1]);
          acc[r][2] = fmaf(v, ((const float*)&w[kk])[2], acc[r][2]);
          acc[r][3] = fmaf(v, ((const float*)&w[kk])[3], acc[r][3]);
        }
      }
    }
    // h part, K=128
    for (int k=0;k<HLN;k+=4){
      float4 w[4];
      #pragma unroll
      for (int kk=0;kk<4;kk++) w[kk] = *(const float4*)&WhhT4[(k+kk)*G4 + u*4];
      #pragma unroll
      for (int r=0;r<4;r++){
        float4 hv = *(const float4*)&hs[cur][r04+r][k];
        #pragma unroll
        for (int kk=0;kk<4;kk++){
          float v = ((const float*)&hv)[kk];
          acc[r][0] = fmaf(v, ((const float*)&w[kk])[0], acc[r][0]);
          acc[r][1] = fmaf(v, ((const float*)&w[kk])[1], acc[r][1]);
          acc[r][2] = fmaf(v, ((const float*)&w[kk])[2], acc[r][2]);
          acc[r][3] = fmaf(v, ((const float*)&w[kk])[3], acc[r][3]);
        }
      }
    }
    // gates in-register (i,f,g,o)
    #pragma unroll
    for (int r=0;r<4;r++){
      float c = sigf(acc[r][1])*creg[r] + sigf(acc[r][0])*tanhf(acc[r][2]);
      creg[r] = c;
      hs[cur^1][r04+r][u] = sigf(acc[r][3])*tanhf(c);
    }
    __syncthreads();
    cur ^= 1;
  }
  // ---- fused output MLP: cat = [h_final (hs[cur]), g_last (xs[cur^1])] ----
  float fa[4];
  #pragma unroll
  for (int r=0;r<4;r++) fa[r] = bfv[u];
  for (int k=0;k<HLN;k++){
    float wf = Wf[k*FHN + u];
    #pragma unroll
    for (int r=0;r<4;r++) fa[r] = fmaf(hs[cur][r04+r][k], wf, fa[r]);
  }
  for (int k=0;k<CC;k++){
    float wf = Wf[(HLN+k)*FHN + u];
    #pragma unroll
    for (int r=0;r<4;r++) fa[r] = fmaf(xs[cur^1][r04+r][k], wf, fa[r]);
  }
  float wo = Wo[u];
  #pragma unroll
  for (int r=0;r<4;r++) fa[r] = fmaxf(fa[r], 0.f) * wo;
  // reduce over 128 units per row; reuse dead hs buffer as scratch
  float* red = (float*)hs[cur^1];
  __syncthreads();
  #pragma unroll
  for (int r=0;r<4;r++) red[(r04+r)*FHN + u] = fa[r];
  __syncthreads();
  for (int s=64;s>=1;s>>=1){
    if (u < s){
      #pragma unroll
      for (int r=0;r<4;r++) red[(r04+r)*FHN + u] += red[(r04+r)*FHN + u + s];
    }
    __syncthreads();
  }
  if (u == 0){
    #pragma unroll
    for (int r=0;r<4;r++) out[r0 + r04 + r] = red[(r04+r)*FHN] + bo[0];
  }
}

// ---------------- launch ----------------
extern "C" void kernel_launch(void* const* d_in, const int* in_sizes, int n_in,
                              void* d_out, int out_size, void* d_ws, size_t ws_size,
                              hipStream_t stream) {
  const float* x_seq  = (const float*)d_in[0];
  const float* W1     = (const float*)d_in[1];
  const float* a_src1 = (const float*)d_in[2];
  const float* a_dst1 = (const float*)d_in[3];
  const float* b1     = (const float*)d_in[4];
  const float* W2     = (const float*)d_in[5];
  const float* a_src2 = (const float*)d_in[6];
  const float* a_dst2 = (const float*)d_in[7];
  const float* b2     = (const float*)d_in[8];
  const float* W_ih   = (const float*)d_in[9];
  const float* W_hh   = (const float*)d_in[10];
  const float* b_ih   = (const float*)d_in[11];
  const float* b_hh   = (const float*)d_in[12];
  const float* Wf     = (const float*)d_in[13];
  const float* bfv    = (const float*)d_in[14];
  const float* Wo     = (const float*)d_in[15];
  const float* bo     = (const float*)d_in[16];
  const int*   ei     = (const int*)d_in[17];
  const int* e_src = ei;
  const int* e_dst = ei + EE;
  float* out = (float*)d_out;

  char* w = (char*)d_ws;
  auto alloc = [&](size_t bytes)->char*{
    char* p = w; w += (bytes + 255) & ~(size_t)255; return p;
  };
  float* als   = (float*)alloc((size_t)BT*NN*HH*4);
  float* ald   = (float*)alloc((size_t)BT*NN*HH*4);
  float* alp   = (float*)alloc((size_t)BT*NE*HH*4);   // logits -> alpha (position-indexed)
  float* gat1  = (float*)alloc((size_t)BT*NN*CC*4);
  float* gbuf  = (float*)alloc((size_t)BT*NN*CC*4);   // final GAT output g
  float* WihT4 = (float*)alloc((size_t)64*512*4);
  float* WhhT4 = (float*)alloc((size_t)128*512*4);
  float* bias4 = (float*)alloc((size_t)512*4);
  float* wt    = (float*)alloc((size_t)768*4);
  int* cnt     = (int*)alloc((size_t)2*NN*4);
  int* cur     = cnt + NN;
  int* ptr     = (int*)alloc((size_t)(NN+1)*4);
  int* idxa    = (int*)alloc((size_t)NE*4);
  int* srcs    = (int*)alloc((size_t)NE*4);
  int* dstp    = (int*)alloc((size_t)NE*4);

  // CSR build (same graph for all 16 instances)
  k_zero<<<(2*NN+255)/256, 256, 0, stream>>>(cnt, 2*NN);
  k_count<<<(NE+255)/256, 256, 0, stream>>>(e_dst, cnt);
  k_scan<<<1, 1024, 0, stream>>>(cnt, ptr);
  k_scatter<<<(NE+255)/256, 256, 0, stream>>>(e_dst, ptr, cur, idxa);
  k_sortseg<<<(NN+255)/256, 256, 0, stream>>>(ptr, idxa, e_src, srcs, dstp);
  k_wtrans<<<(64*512+128*512+512+255)/256, 256, 0, stream>>>(W_ih, W_hh, b_ih, b_hh, WihT4, WhhT4, bias4);
  k_wtil<<<3, 256, 0, stream>>>(W1, a_src1, a_dst1, W2, a_src2, a_dst2, wt);

  // GAT layer 1 (aggregation in x-space: 32-dim gathers)
  k_coef2<32><<<(BT*NN*HH+255)/256, 256, 0, stream>>>(x_seq, wt, wt+128, als, ald);
  k_logits<<<(BT*NE+255)/256, 256, 0, stream>>>(srcs, dstp, als, ald, alp);
  k_alpha<<<(BT*NN*HH+255)/256, 256, 0, stream>>>(ptr, alp);
  k_gat_out<32><<<dim3(NN/16, BT), 256, 0, stream>>>(ptr, srcs, alp, x_seq, W1, b1, gat1);

  // GAT layer 2 (64-dim gathers from L2-resident gat1)
  k_coef2<64><<<(BT*NN*HH+255)/256, 256, 0, stream>>>(gat1, wt+256, wt+512, als, ald);
  k_logits<<<(BT*NE+255)/256, 256, 0, stream>>>(srcs, dstp, als, ald, alp);
  k_alpha<<<(BT*NN*HH+255)/256, 256, 0, stream>>>(ptr, alp);
  k_gat_out<64><<<dim3(NN/16, BT), 256, 0, stream>>>(ptr, srcs, alp, gat1, W2, b2, gbuf);

  // LSTM over time + fused output MLP
  k_lstm3<<<BB*NN/ROWS, 512, 0, stream>>>(gbuf, WihT4, WhhT4, bias4, Wf, bfv, Wo, bo, out);
}